// Round 11
// baseline (549.390 us; speedup 1.0000x reference)
//
#include <hip/hip_runtime.h>
#include <cstdint>

typedef _Float16 half8 __attribute__((ext_vector_type(8)));
typedef float f32x4 __attribute__((ext_vector_type(4)));
typedef float f32x4u __attribute__((ext_vector_type(4), aligned(4)));
typedef unsigned short u16;

typedef __attribute__((address_space(3))) char lds_char;
typedef const __attribute__((address_space(1))) char glb_char;
#define GLOAD16(gp, lp) \
  __builtin_amdgcn_global_load_lds((glb_char*)(gp), (lds_char*)(lp), 16, 0, 0)

#define B_ 64
#define NQ 197
#define C_ 768
#define H_ 12
#define NKV 261
#define RKV 16768   // 131*128 padded kv rows
#define RQ  12672   // 99*128 padded src rows

#define X_OFF    0
#define ATTN_OFF 9682944
#define SAL_OFF  39488256

// workspace offsets (bytes)
#define WS_WQKV  0u           // 2304*768 fp16 = 3,538,944
#define WS_WP    3538944u     // 768*768 fp16  = 1,179,648
#define WS_KV    4718592u     // 16768*768 fp16 = 25,755,648
#define WS_QKV   30474240u    // 16768*2304 fp16 = 77,266,944
#define WS_O     107741184u   // 12672*768 fp16 = 19,464,192
// saliency scratch aliases the kvh region (kvh is dead after gemm_bt<0>)
#define WS_Q0    (WS_KV + 0u)        // 64*768 f32 = 196,608
#define WS_P     (WS_KV + 196608u)   // 64*12*261 f32 = 801,792
#define WS_R     (WS_KV + 1048576u)  // 64*12*768 f32 = 2,359,296

__device__ __forceinline__ u16 f2h(float f) {
  return __builtin_bit_cast(u16, (_Float16)f);
}

// ---------------- prep: weight conversion + fused kv build (one launch) -------
__global__ void prep(const float* __restrict__ Wq, const float* __restrict__ Wk,
                     const float* __restrict__ Wv, const float* __restrict__ Wp,
                     const float* __restrict__ src, const float* __restrict__ vtm,
                     u16* __restrict__ Wqkv, u16* __restrict__ Wph,
                     u16* __restrict__ kvh) {
  const int bid = blockIdx.x;
  if (bid < 1152) {
    // weight conversion: 4 * 147456 float4-groups
    for (int i = bid * 256 + threadIdx.x; i < 4 * 147456; i += 1152 * 256) {
      int g = i / 147456;
      int idx = (i - g * 147456) * 4;
      const float* s = (g == 0) ? Wq : (g == 1) ? Wk : (g == 2) ? Wv : Wp;
      float4 v = *(const float4*)(s + idx);
      union { u16 u[4]; uint64_t q; } o;
      o.u[0] = f2h(v.x); o.u[1] = f2h(v.y); o.u[2] = f2h(v.z); o.u[3] = f2h(v.w);
      u16* d = (g < 3) ? (Wqkv + (size_t)g * 589824 + idx) : (Wph + idx);
      *(uint64_t*)d = o.q;
    }
  } else {
    // fused kv build (fp16, padded rows zeroed): RKV*192 u64-groups
    for (int i = (bid - 1152) * 256 + threadIdx.x; i < RKV * 192; i += 2048 * 256) {
      int row = i / 192;
      int c = (i - row * 192) * 4;
      union { u16 u[4]; uint64_t q; } o;
      if (row < B_ * NKV) {
        int b = row / NKV, t = row - b * NKV;
        const float* p;
        if (t < NQ) p = src + ((size_t)b * NQ + t) * 768 + c;
        else {
          int tt = t - NQ;
          p = vtm + ((size_t)((tt >> 4) * 64 + b) * 16 + (tt & 15)) * 768 + c;
        }
        float4 v = *(const float4*)p;
        o.u[0] = f2h(v.x); o.u[1] = f2h(v.y); o.u[2] = f2h(v.z); o.u[3] = f2h(v.w);
      } else {
        o.q = 0;
      }
      *(uint64_t*)(kvh + (size_t)row * 768 + c) = o.q;
    }
  }
}

// ---------------- GEMM: C[m][n] = sum_k A[m][k]*B[n][k]  (fp16 in, fp32 acc) ----
// m97 structure + nt-fast block order. LDS XOR-swizzle via pre-swizzled source.
// EPI=0: fp16 C through LDS-transposed epilogue. EPI=1: fp32 + bias direct.
template <int EPI>
__launch_bounds__(256, 4)
__global__ void gemm_bt(const u16* __restrict__ A, const u16* __restrict__ Bw,
                        void* __restrict__ Cp, const float* __restrict__ bias,
                        int ntiles, int kdim, int lda, int ldb, int ldc, int mlimit) {
  __shared__ u16 sAB[2][128 * 64];
  u16* sA = sAB[0];
  u16* sB = sAB[1];
  const int tid = threadIdx.x;
  const int w = tid >> 6, lane = tid & 63;
  int bid = blockIdx.x;
  {  // bijective XCD swizzle (m204 formula, any grid size)
    const int nwg = gridDim.x;
    const int q = nwg >> 3, rr = nwg & 7;
    const int xcd = bid & 7, loc = bid >> 3;
    bid = (xcd < rr ? xcd * (q + 1) : rr * (q + 1) + (xcd - rr) * q) + loc;
  }
  const int nt = bid % ntiles, mt = bid / ntiles;
  const int wr = w >> 1, wc = w & 1;
  const int fr = lane & 15, g = lane >> 4;
  const int frs = fr & 7;

  const u16* gAp[4];
  const u16* gBp[4];
#pragma unroll
  for (int j = 0; j < 4; ++j) {
    const int lin = j * 256 + tid;
    const int r = lin >> 3;
    const int c = (lin & 7) ^ (r & 7);   // inverse swizzle on the source
    gAp[j] = A + (size_t)(mt * 128 + r) * lda + c * 8;
    gBp[j] = Bw + (size_t)(nt * 128 + r) * ldb + c * 8;
  }

  const f32x4 vz = {0.f, 0.f, 0.f, 0.f};
  f32x4 acc[4][4];
#pragma unroll
  for (int i = 0; i < 4; ++i)
#pragma unroll
    for (int j = 0; j < 4; ++j) acc[i][j] = vz;

  for (int k0 = 0; k0 < kdim; k0 += 64) {
    __syncthreads();
#pragma unroll
    for (int j = 0; j < 4; ++j)
      GLOAD16(gAp[j] + k0, ((char*)sA) + (j * 256 + tid) * 16);
#pragma unroll
    for (int j = 0; j < 4; ++j)
      GLOAD16(gBp[j] + k0, ((char*)sB) + (j * 256 + tid) * 16);
    __syncthreads();
#pragma unroll
    for (int kk = 0; kk < 2; ++kk) {
      half8 af[4], bf[4];
      const int sw = ((kk * 4 + g) ^ frs) * 8;
#pragma unroll
      for (int i = 0; i < 4; ++i) {
        af[i] = *(const half8*)&sA[(wr * 64 + i * 16 + fr) * 64 + sw];
        bf[i] = *(const half8*)&sB[(wc * 64 + i * 16 + fr) * 64 + sw];
      }
#pragma unroll
      for (int mi = 0; mi < 4; ++mi)
#pragma unroll
        for (int ni = 0; ni < 4; ++ni)
          acc[mi][ni] =
              __builtin_amdgcn_mfma_f32_16x16x32_f16(af[mi], bf[ni], acc[mi][ni], 0, 0, 0);
    }
  }

  if (EPI == 0) {
    // fp16 C via LDS transpose: tile[128][128] u16 (32KB, aliases sAB),
    // XOR-swizzled (n ^ ((m&7)<<3) in u16 units).
    u16* tile = sAB[0];
    __syncthreads();
#pragma unroll
    for (int mi = 0; mi < 4; ++mi)
#pragma unroll
      for (int ni = 0; ni < 4; ++ni) {
        const int n = wc * 64 + ni * 16 + fr;
#pragma unroll
        for (int r = 0; r < 4; ++r) {
          const int m = wr * 64 + mi * 16 + (g << 2) + r;
          tile[m * 128 + (n ^ ((m & 7) << 3))] = f2h(acc[mi][ni][r]);
        }
      }
    __syncthreads();
    const int r8 = lane >> 3, ck = lane & 7;
#pragma unroll
    for (int s = 0; s < 4; ++s) {
      const int row = w * 32 + s * 8 + r8;
      const int gm = mt * 128 + row;
#pragma unroll
      for (int hc = 0; hc < 2; ++hc) {
        const int nb = hc * 64 + ck * 8;
        uint4 v = *(const uint4*)&tile[row * 128 + (nb ^ ((row & 7) << 3))];
        *(uint4*)&((u16*)Cp)[(size_t)gm * ldc + nt * 128 + nb] = v;
      }
    }
  } else {
    const int rbase = (lane >> 4) << 2;
#pragma unroll
    for (int mi = 0; mi < 4; ++mi) {
#pragma unroll
      for (int ni = 0; ni < 4; ++ni) {
        const int n = nt * 128 + wc * 64 + ni * 16 + fr;
#pragma unroll
        for (int r = 0; r < 4; ++r) {
          const int m = mt * 128 + wr * 64 + mi * 16 + rbase + r;
          if (m < mlimit) ((float*)Cp)[(size_t)m * ldc + n] = acc[mi][ni][r] + bias[n];
        }
      }
    }
  }
}

// ---------------- attention: r8 structure at 512 threads (8 waves/block) ------
// Swapped QK^T (S^T = mfma(K,Q)); lane(fr,g) holds P[q=fr][k=16jt+4g+ri];
// 0.125 folded into Q. In-register softmax (2 shfls). attn_out: one f32x4
// store per jt per lane (proven clean: FETCH 37MB, VGPR 68). PV via packed
// fp16 __shfl redistribution. 8 waves share one K+Vt staging -> 16 waves/CU.
// LDS: K swz [272][64] @0 (34816) + Vt swz [64][288] @34816 (36864) = 71680.
#define ATT_K_OFF  0
#define ATT_VT_OFF 34816
#define ATT_LDS_TOT 71680

__launch_bounds__(512, 4)
__global__ void attn_kernel(const u16* __restrict__ qkv, float* __restrict__ out,
                            u16* __restrict__ Oh) {
  extern __shared__ char smem[];
  const int tid = threadIdx.x, w = tid >> 6, lane = tid & 63;
  const int bid = blockIdx.x;
  const int b = bid / 12, h = bid - b * 12;
  const size_t rowbase = (size_t)b * NKV;

  // stage K: rows 0..271, 64 cols, 16B-chunk XOR swizzle
  for (int i = tid; i < 272 * 8; i += 512) {
    const int row = i >> 3, c8 = (i & 7) << 3;
    uint4 v = *(const uint4*)(qkv + (rowbase + row) * 2304 + 768 + h * 64 + c8);
    *(uint4*)(smem + ATT_K_OFF + row * 128 + ((c8 * 2) ^ ((row & 7) << 4))) = v;
  }
  // stage V transposed: Vt[d][k] swizzled, k rows 0..287
  for (int i = tid; i < 288 * 8; i += 512) {
    const int row = i >> 3, c8 = (i & 7) << 3;
    union { u16 u[8]; uint4 v; } t;
    t.v = *(const uint4*)(qkv + (rowbase + row) * 2304 + 1536 + h * 64 + c8);
#pragma unroll
    for (int j = 0; j < 8; ++j) {
      const int d = c8 + j;
      const int sw = ((row < 256) ? (d & 7) : (d & 3)) << 4;
      *(u16*)(smem + ATT_VT_OFF + d * 576 + ((row * 2) ^ sw)) = t.u[j];
    }
  }
  __syncthreads();

  const int fr = lane & 15, g = lane >> 4;
  const f32x4 vz = {0.f, 0.f, 0.f, 0.f};

  for (int qt = w; qt < 13; qt += 8) {
    // Q as B-fragment, scale folded in (exact pow2)
    const u16* qp = qkv + (rowbase + qt * 16 + fr) * 2304 + h * 64 + g * 8;
    half8 bq0 = *(const half8*)qp;
    half8 bq1 = *(const half8*)(qp + 32);
    bq0 = bq0 * (_Float16)0.125;
    bq1 = bq1 * (_Float16)0.125;

    f32x4 sc[17];
#pragma unroll
    for (int jt = 0; jt < 17; ++jt) {
      const int krow = jt * 16 + fr;
      const int swz = (krow & 7) << 4;
      half8 ak0 = *(const half8*)(smem + ATT_K_OFF + krow * 128 + ((g * 16) ^ swz));
      half8 ak1 = *(const half8*)(smem + ATT_K_OFF + krow * 128 + ((64 + g * 16) ^ swz));
      f32x4 a = vz;
      a = __builtin_amdgcn_mfma_f32_16x16x32_f16(ak0, bq0, a, 0, 0, 0);
      a = __builtin_amdgcn_mfma_f32_16x16x32_f16(ak1, bq1, a, 0, 0, 0);
      sc[jt] = a;  // P[q=fr][k=16jt+4g+ri]
    }
    // mask: only jt=16 can be out of range (k=256+4g+ri, valid iff 4g+ri<5)
#pragma unroll
    for (int ri = 0; ri < 4; ++ri)
      sc[16][ri] = (4 * g + ri < 5) ? sc[16][ri] : -3.0e38f;

    // softmax over k: in-register + 2 cross-group shfls
    float m = -3.0e38f;
#pragma unroll
    for (int jt = 0; jt < 17; ++jt)
      m = fmaxf(m, fmaxf(fmaxf(sc[jt][0], sc[jt][1]), fmaxf(sc[jt][2], sc[jt][3])));
    m = fmaxf(m, __shfl_xor(m, 16, 64));
    m = fmaxf(m, __shfl_xor(m, 32, 64));
    float s = 0.f;
#pragma unroll
    for (int jt = 0; jt < 17; ++jt)
#pragma unroll
      for (int ri = 0; ri < 4; ++ri) {
        float e = __expf(sc[jt][ri] - m);
        sc[jt][ri] = e;
        s += e;
      }
    s += __shfl_xor(s, 16, 64);
    s += __shfl_xor(s, 32, 64);
    const float inv = 1.f / s;
#pragma unroll
    for (int jt = 0; jt < 17; ++jt)
#pragma unroll
      for (int ri = 0; ri < 4; ++ri) sc[jt][ri] *= inv;

    // attn_out: one dwordx4 per jt per lane (clean traffic, verified r8)
    const int q = qt * 16 + fr;
    if (q < NQ) {
      float* ob = out + ATTN_OFF + (size_t)bid * NQ * NQ + (size_t)q * NQ + 4 * g;
#pragma unroll
      for (int jt = 0; jt < 12; ++jt)
        *(f32x4u*)(ob + jt * 16) = sc[jt];
      if (g == 0) *(f32x4u*)(ob + 192) = sc[12];       // cols 192..195
      else if (g == 1) ob[192] = sc[12][0];            // col 196
    }

    // pack P rows to fp16 pairs (per lane: q=fr, k=16jt+4g+{0,1},{2,3})
    uint32_t u01[17], u23[17];
#pragma unroll
    for (int jt = 0; jt < 17; ++jt) {
      u01[jt] = (uint32_t)f2h(sc[jt][0]) | ((uint32_t)f2h(sc[jt][1]) << 16);
      u23[jt] = (uint32_t)f2h(sc[jt][2]) | ((uint32_t)f2h(sc[jt][3]) << 16);
    }
    // P @ V : A-frag needs P[q=fr][k = kt*32 + 8g + j]
    f32x4 oa[4] = {vz, vz, vz, vz};
    const int srcA = fr + ((lane & 16) << 1);  // fr + 32*(g&1)
    const bool odd = (lane & 32) != 0;         // (g>>1): use odd jt tile
#pragma unroll
    for (int kt = 0; kt < 9; ++kt) {
      const uint32_t e0 = u01[2 * kt];
      const uint32_t e1 = u23[2 * kt];
      const uint32_t o0 = (kt < 8) ? u01[2 * kt + 1] : 0u;
      const uint32_t o1 = (kt < 8) ? u23[2 * kt + 1] : 0u;
      const int Ea = __shfl((int)e0, srcA, 64);
      const int Eb = __shfl((int)e1, srcA, 64);
      const int Ec = __shfl((int)e0, srcA + 16, 64);
      const int Ed = __shfl((int)e1, srcA + 16, 64);
      const int Oa = __shfl((int)o0, srcA, 64);
      const int Ob = __shfl((int)o1, srcA, 64);
      const int Oc = __shfl((int)o0, srcA + 16, 64);
      const int Od = __shfl((int)o1, srcA + 16, 64);
      union { int a[4]; half8 hv; } pa;
      pa.a[0] = odd ? Oa : Ea;
      pa.a[1] = odd ? Ob : Eb;
      pa.a[2] = odd ? Oc : Ec;
      pa.a[3] = odd ? Od : Ed;
#pragma unroll
      for (int dt = 0; dt < 4; ++dt) {
        const int vrow = dt * 16 + fr;
        const int sw = ((kt < 8) ? (vrow & 7) : (vrow & 3)) << 4;
        half8 bv = *(const half8*)(smem + ATT_VT_OFF + vrow * 576 + ((kt * 64 + g * 16) ^ sw));
        oa[dt] = __builtin_amdgcn_mfma_f32_16x16x32_f16(pa.hv, bv, oa[dt], 0, 0, 0);
      }
    }
    // store O (fp16): q-row = qt*16 + 4g + ri, d = dt*16 + fr
#pragma unroll
    for (int dt = 0; dt < 4; ++dt)
#pragma unroll
      for (int ri = 0; ri < 4; ++ri) {
        const int qr = qt * 16 + 4 * g + ri;
        if (qr < NQ)
          Oh[((size_t)b * NQ + qr) * 768 + h * 64 + dt * 16 + fr] = f2h(oa[dt][ri]);
      }
  }
}

// ---------------- fp32 saliency side path (exact top-k), parallelized --------
__global__ void sal_q0(const float* __restrict__ src, const float* __restrict__ Wq,
                       float* __restrict__ q0ws) {
  const int bid = blockIdx.x;            // 64*192
  const int b = bid / 192, cb = (bid - (bid / 192) * 192) * 4;
  const int w = threadIdx.x >> 6, lane = threadIdx.x & 63;
  const int c = cb + w;
  const float* srow = src + (size_t)b * NQ * 768;
  const float* wrow = Wq + (size_t)c * 768;
  float acc = 0.f;
#pragma unroll
  for (int j = 0; j < 12; ++j)
    acc = fmaf(srow[lane + 64 * j], wrow[lane + 64 * j], acc);
#pragma unroll
  for (int off = 32; off >= 1; off >>= 1) acc += __shfl_xor(acc, off, 64);
  if (lane == 0) q0ws[(size_t)b * 768 + c] = acc;
}

__global__ void sal_r(const float* __restrict__ q0ws, const float* __restrict__ Wk,
                      float* __restrict__ rws) {
  const int bid = blockIdx.x;            // 64*12*3 = 2304
  const int b = bid / 36, rem = bid - (bid / 36) * 36;
  const int h = rem / 3, cc = (rem - (rem / 3) * 3) * 256;
  const int c = cc + threadIdx.x;
  __shared__ float sq[64];
  if (threadIdx.x < 64) sq[threadIdx.x] = q0ws[(size_t)b * 768 + h * 64 + threadIdx.x];
  __syncthreads();
  float acc = 0.f;
#pragma unroll
  for (int dh = 0; dh < 64; ++dh)
    acc = fmaf(sq[dh], Wk[(size_t)(h * 64 + dh) * 768 + c], acc);
  rws[((size_t)b * 12 + h) * 768 + c] = acc;
}

__global__ void sal_p(const float* __restrict__ src, const float* __restrict__ vtm,
                      const float* __restrict__ rws, float* __restrict__ pws) {
  const int bid = blockIdx.x;            // 64*261 = 16704
  const int b = bid / NKV, kk = bid - (bid / NKV) * NKV;
  const int w = threadIdx.x >> 6, lane = threadIdx.x & 63;
  const float* kvrow;
  if (kk < NQ) kvrow = src + ((size_t)b * NQ + kk) * 768;
  else {
    int tt = kk - NQ;
    kvrow = vtm + ((size_t)((tt >> 4) * 64 + b) * 16 + (tt & 15)) * 768;
  }
  float v[12];
#pragma unroll
  for (int j = 0; j < 12; ++j) v[j] = kvrow[lane + 64 * j];
  for (int hh = w; hh < 12; hh += 4) {
    const float* rrow = rws + ((size_t)b * 12 + hh) * 768;
    float acc = 0.f;
#pragma unroll
    for (int j = 0; j < 12; ++j) acc = fmaf(v[j], rrow[lane + 64 * j], acc);
#pragma unroll
    for (int off = 32; off >= 1; off >>= 1) acc += __shfl_xor(acc, off, 64);
    if (lane == 0) pws[((size_t)b * 12 + hh) * NKV + kk] = acc * 0.125f;
  }
}

__global__ void sal_top(const float* __restrict__ src, const float* __restrict__ pws,
                        float* __restrict__ out) {
  const int b = blockIdx.x, tid = threadIdx.x, w = tid >> 6, lane = tid & 63;
  __shared__ float s_p[12][272];
  __shared__ float s_sal[196];
  __shared__ int s_top[16];
  for (int i = tid; i < 12 * NKV; i += 256)
    s_p[i / NKV][i - (i / NKV) * NKV] = pws[(size_t)b * 12 * NKV + i];
  __syncthreads();
  for (int hh = w; hh < 12; hh += 4) {
    float m = -3.0e38f;
    for (int kk = lane; kk < NKV; kk += 64) m = fmaxf(m, s_p[hh][kk]);
#pragma unroll
    for (int off = 32; off >= 1; off >>= 1) m = fmaxf(m, __shfl_xor(m, off, 64));
    float s = 0.f;
    for (int kk = lane; kk < NKV; kk += 64) s += expf(s_p[hh][kk] - m);
#pragma unroll
    for (int off = 32; off >= 1; off >>= 1) s += __shfl_xor(s, off, 64);
    for (int kk = lane; kk < NKV; kk += 64) s_p[hh][kk] = expf(s_p[hh][kk] - m) / s;
  }
  __syncthreads();
  if (tid < 196) {
    float a = 0.f;
#pragma unroll
    for (int hh = 0; hh < 12; ++hh) a += s_p[hh][tid + 1];
    s_sal[tid] = a * (1.0f / 12.0f);
  }
  __syncthreads();
  if (w == 0) {
    float v[4];
    int idx[4];
    bool taken[4];
#pragma unroll
    for (int j = 0; j < 4; ++j) {
      int id = lane + 64 * j;
      idx[j] = id;
      taken[j] = false;
      v[j] = (id < 196) ? s_sal[id] : -3.0e38f;
    }
    for (int round = 0; round < 16; ++round) {
      float best = -3.0e38f;
      int bi = 1 << 30;
#pragma unroll
      for (int j = 0; j < 4; ++j)
        if (!taken[j] && v[j] > best) { best = v[j]; bi = idx[j]; }
#pragma unroll
      for (int off = 1; off <= 32; off <<= 1) {
        float ov = __shfl_xor(best, off, 64);
        int oi = __shfl_xor(bi, off, 64);
        if (ov > best || (ov == best && oi < bi)) { best = ov; bi = oi; }
      }
#pragma unroll
      for (int j = 0; j < 4; ++j)
        if (idx[j] == bi) taken[j] = true;
      if (lane == 0) s_top[round] = bi;
    }
  }
  __syncthreads();
  for (int i = 0; i < 16; ++i) {
    int id = s_top[i];
    for (int c = tid; c < 768; c += 256)
      out[SAL_OFF + ((size_t)b * 16 + i) * 768 + c] = src[((size_t)b * NQ + id) * 768 + c];
  }
}

// ---------------- launcher ----------------------------------------------------
extern "C" void kernel_launch(void* const* d_in, const int* in_sizes, int n_in,
                              void* d_out, int out_size, void* d_ws, size_t ws_size,
                              hipStream_t stream) {
  const float* src = (const float*)d_in[0];
  const float* vtm = (const float*)d_in[1];
  const float* Wq = (const float*)d_in[2];
  const float* Wk = (const float*)d_in[3];
  const float* Wv = (const float*)d_in[4];
  const float* Wp = (const float*)d_in[5];
  const float* bp = (const float*)d_in[6];
  float* out = (float*)d_out;
  char* ws = (char*)d_ws;

  u16* Wqkv = (u16*)(ws + WS_WQKV);
  u16* Wph = (u16*)(ws + WS_WP);
  u16* kvh = (u16*)(ws + WS_KV);
  u16* QKV = (u16*)(ws + WS_QKV);
  u16* Oh = (u16*)(ws + WS_O);
  float* q0ws = (float*)(ws + WS_Q0);
  float* pws = (float*)(ws + WS_P);
  float* rws = (float*)(ws + WS_R);

  prep<<<3200, 256, 0, stream>>>(Wq, Wk, Wv, Wp, src, vtm, Wqkv, Wph, kvh);
  // QKV = kv @ [Wq;Wk;Wv]^T   (M=16768, N=2304, K=768) — nt-fast order
  gemm_bt<0><<<131 * 18, 256, 0, stream>>>(kvh, Wqkv, QKV, nullptr, 18, 768, 768, 768, 2304, 0);
  hipFuncSetAttribute((const void*)attn_kernel, hipFuncAttributeMaxDynamicSharedMemorySize,
                      ATT_LDS_TOT);
  attn_kernel<<<B_ * H_, 512, ATT_LDS_TOT, stream>>>(QKV, out, Oh);
  // x = O @ Wp^T + bp  (M=12672, real 12608, N=768, K=768) — nt-fast order
  gemm_bt<1><<<99 * 6, 256, 0, stream>>>(Oh, Wph, out, bp, 6, 768, 768, 768, 768, 12608);
  // fp32 saliency side path (exact top-k), parallelized — scratch aliases kvh
  sal_q0<<<64 * 192, 256, 0, stream>>>(src, Wq, q0ws);
  sal_r<<<64 * 12 * 3, 256, 0, stream>>>(q0ws, Wk, rws);
  sal_p<<<64 * NKV, 256, 0, stream>>>(src, vtm, rws, pws);
  sal_top<<<64, 256, 0, stream>>>(src, pws, out);
}

// Round 12
// 283.838 us; speedup vs baseline: 1.9356x; 1.9356x over previous
//
#include <hip/hip_runtime.h>
#include <cstdint>

typedef _Float16 half8 __attribute__((ext_vector_type(8)));
typedef float f32x4 __attribute__((ext_vector_type(4)));
typedef unsigned short u16;

typedef __attribute__((address_space(3))) char lds_char;
typedef const __attribute__((address_space(1))) char glb_char;
#define GLOAD16(gp, lp) \
  __builtin_amdgcn_global_load_lds((glb_char*)(gp), (lds_char*)(lp), 16, 0, 0)

#define B_ 64
#define NQ 197
#define C_ 768
#define H_ 12
#define NKV 261
#define RKV 16768   // 131*128 padded kv rows
#define RQ  12672   // 99*128 padded src rows

#define X_OFF    0
#define ATTN_OFF 9682944
#define SAL_OFF  39488256

// workspace offsets (bytes)
#define WS_WQKV  0u           // 2304*768 fp16 = 3,538,944
#define WS_WP    3538944u     // 768*768 fp16  = 1,179,648
#define WS_KV    4718592u     // 16768*768 fp16 = 25,755,648
#define WS_QKV   30474240u    // 16768*2304 fp16 = 77,266,944
#define WS_O     107741184u   // 12672*768 fp16 = 19,464,192
// saliency scratch aliases the kvh region (kvh is dead after gemm_bt<0>)
#define WS_Q0    (WS_KV + 0u)        // 64*768 f32 = 196,608
#define WS_P     (WS_KV + 196608u)   // 64*12*261 f32 = 801,792
#define WS_R     (WS_KV + 1048576u)  // 64*12*768 f32 = 2,359,296

__device__ __forceinline__ u16 f2h(float f) {
  return __builtin_bit_cast(u16, (_Float16)f);
}

// ---------------- prep: weight conversion + fused kv build (one launch) -------
__global__ void prep(const float* __restrict__ Wq, const float* __restrict__ Wk,
                     const float* __restrict__ Wv, const float* __restrict__ Wp,
                     const float* __restrict__ src, const float* __restrict__ vtm,
                     u16* __restrict__ Wqkv, u16* __restrict__ Wph,
                     u16* __restrict__ kvh) {
  const int bid = blockIdx.x;
  if (bid < 1152) {
    // weight conversion: 4 * 147456 float4-groups
    for (int i = bid * 256 + threadIdx.x; i < 4 * 147456; i += 1152 * 256) {
      int g = i / 147456;
      int idx = (i - g * 147456) * 4;
      const float* s = (g == 0) ? Wq : (g == 1) ? Wk : (g == 2) ? Wv : Wp;
      float4 v = *(const float4*)(s + idx);
      union { u16 u[4]; uint64_t q; } o;
      o.u[0] = f2h(v.x); o.u[1] = f2h(v.y); o.u[2] = f2h(v.z); o.u[3] = f2h(v.w);
      u16* d = (g < 3) ? (Wqkv + (size_t)g * 589824 + idx) : (Wph + idx);
      *(uint64_t*)d = o.q;
    }
  } else {
    // fused kv build (fp16, padded rows zeroed): RKV*192 u64-groups
    for (int i = (bid - 1152) * 256 + threadIdx.x; i < RKV * 192; i += 2048 * 256) {
      int row = i / 192;
      int c = (i - row * 192) * 4;
      union { u16 u[4]; uint64_t q; } o;
      if (row < B_ * NKV) {
        int b = row / NKV, t = row - b * NKV;
        const float* p;
        if (t < NQ) p = src + ((size_t)b * NQ + t) * 768 + c;
        else {
          int tt = t - NQ;
          p = vtm + ((size_t)((tt >> 4) * 64 + b) * 16 + (tt & 15)) * 768 + c;
        }
        float4 v = *(const float4*)p;
        o.u[0] = f2h(v.x); o.u[1] = f2h(v.y); o.u[2] = f2h(v.z); o.u[3] = f2h(v.w);
      } else {
        o.q = 0;
      }
      *(uint64_t*)(kvh + (size_t)row * 768 + c) = o.q;
    }
  }
}

// ---------------- GEMM: C[m][n] = sum_k A[m][k]*B[n][k]  (fp16 in, fp32 acc) ----
// m97 structure + nt-fast block order. LDS XOR-swizzle via pre-swizzled source.
// EPI=0: fp16 C through LDS-transposed epilogue. EPI=1: fp32 + bias direct.
template <int EPI>
__launch_bounds__(256, 4)
__global__ void gemm_bt(const u16* __restrict__ A, const u16* __restrict__ Bw,
                        void* __restrict__ Cp, const float* __restrict__ bias,
                        int ntiles, int kdim, int lda, int ldb, int ldc, int mlimit) {
  __shared__ u16 sAB[2][128 * 64];
  u16* sA = sAB[0];
  u16* sB = sAB[1];
  const int tid = threadIdx.x;
  const int w = tid >> 6, lane = tid & 63;
  int bid = blockIdx.x;
  {  // bijective XCD swizzle (m204 formula, any grid size)
    const int nwg = gridDim.x;
    const int q = nwg >> 3, rr = nwg & 7;
    const int xcd = bid & 7, loc = bid >> 3;
    bid = (xcd < rr ? xcd * (q + 1) : rr * (q + 1) + (xcd - rr) * q) + loc;
  }
  const int nt = bid % ntiles, mt = bid / ntiles;
  const int wr = w >> 1, wc = w & 1;
  const int fr = lane & 15, g = lane >> 4;
  const int frs = fr & 7;

  const u16* gAp[4];
  const u16* gBp[4];
#pragma unroll
  for (int j = 0; j < 4; ++j) {
    const int lin = j * 256 + tid;
    const int r = lin >> 3;
    const int c = (lin & 7) ^ (r & 7);   // inverse swizzle on the source
    gAp[j] = A + (size_t)(mt * 128 + r) * lda + c * 8;
    gBp[j] = Bw + (size_t)(nt * 128 + r) * ldb + c * 8;
  }

  const f32x4 vz = {0.f, 0.f, 0.f, 0.f};
  f32x4 acc[4][4];
#pragma unroll
  for (int i = 0; i < 4; ++i)
#pragma unroll
    for (int j = 0; j < 4; ++j) acc[i][j] = vz;

  for (int k0 = 0; k0 < kdim; k0 += 64) {
    __syncthreads();
#pragma unroll
    for (int j = 0; j < 4; ++j)
      GLOAD16(gAp[j] + k0, ((char*)sA) + (j * 256 + tid) * 16);
#pragma unroll
    for (int j = 0; j < 4; ++j)
      GLOAD16(gBp[j] + k0, ((char*)sB) + (j * 256 + tid) * 16);
    __syncthreads();
#pragma unroll
    for (int kk = 0; kk < 2; ++kk) {
      half8 af[4], bf[4];
      const int sw = ((kk * 4 + g) ^ frs) * 8;
#pragma unroll
      for (int i = 0; i < 4; ++i) {
        af[i] = *(const half8*)&sA[(wr * 64 + i * 16 + fr) * 64 + sw];
        bf[i] = *(const half8*)&sB[(wc * 64 + i * 16 + fr) * 64 + sw];
      }
#pragma unroll
      for (int mi = 0; mi < 4; ++mi)
#pragma unroll
        for (int ni = 0; ni < 4; ++ni)
          acc[mi][ni] =
              __builtin_amdgcn_mfma_f32_16x16x32_f16(af[mi], bf[ni], acc[mi][ni], 0, 0, 0);
    }
  }

  if (EPI == 0) {
    // fp16 C via LDS transpose: tile[128][128] u16 (32KB, aliases sAB),
    // XOR-swizzled (n ^ ((m&7)<<3) in u16 units).
    u16* tile = sAB[0];
    __syncthreads();
#pragma unroll
    for (int mi = 0; mi < 4; ++mi)
#pragma unroll
      for (int ni = 0; ni < 4; ++ni) {
        const int n = wc * 64 + ni * 16 + fr;
#pragma unroll
        for (int r = 0; r < 4; ++r) {
          const int m = wr * 64 + mi * 16 + (g << 2) + r;
          tile[m * 128 + (n ^ ((m & 7) << 3))] = f2h(acc[mi][ni][r]);
        }
      }
    __syncthreads();
    const int r8 = lane >> 3, ck = lane & 7;
#pragma unroll
    for (int s = 0; s < 4; ++s) {
      const int row = w * 32 + s * 8 + r8;
      const int gm = mt * 128 + row;
#pragma unroll
      for (int hc = 0; hc < 2; ++hc) {
        const int nb = hc * 64 + ck * 8;
        uint4 v = *(const uint4*)&tile[row * 128 + (nb ^ ((row & 7) << 3))];
        *(uint4*)&((u16*)Cp)[(size_t)gm * ldc + nt * 128 + nb] = v;
      }
    }
  } else {
    const int rbase = (lane >> 4) << 2;
#pragma unroll
    for (int mi = 0; mi < 4; ++mi) {
#pragma unroll
      for (int ni = 0; ni < 4; ++ni) {
        const int n = nt * 128 + wc * 64 + ni * 16 + fr;
#pragma unroll
        for (int r = 0; r < 4; ++r) {
          const int m = mt * 128 + wr * 64 + mi * 16 + rbase + r;
          if (m < mlimit) ((float*)Cp)[(size_t)m * ldc + n] = acc[mi][ni][r] + bias[n];
        }
      }
    }
  }
}

// ---------------- attention: r10 structure at 512 threads (16 waves/CU) -------
// Q=A-frag (0.125 folded); K=B-frag from LDS; wave-parallel softmax; P via
// per-wave 1KB LDS chunk (single-buffered; DS in-order per wave + lgkm drain);
// attn_out col=fr coalesced store (clean traffic, verified). 8 waves share one
// K+Vt staging; __launch_bounds__(512,2) -> VGPR cap 128 >= 72 used -> no spill;
// 2 blocks/CU x 8 waves = 16 waves/CU (2x r10).
// LDS: K swz [272][64] @0 (34816), Vt swz [64][288] @34816 (36864),
//      per-wave P 1KB x8 @71680 (8192). total 79872 x2 = 159744 <= 160K.
#define ATT_LDS_TOT 79872

__launch_bounds__(512, 2)
__global__ void attn_kernel(const u16* __restrict__ qkv, float* __restrict__ out,
                            u16* __restrict__ Oh) {
  extern __shared__ char smem[];
  const int tid = threadIdx.x, w = tid >> 6, lane = tid & 63;
  const int bid = blockIdx.x;
  const int b = bid / 12, h = bid - b * 12;
  const size_t rowbase = (size_t)b * NKV;

  // stage K: rows 0..271, 64 cols
  for (int i = tid; i < 272 * 8; i += 512) {
    const int row = i >> 3, c8 = (i & 7) << 3;
    uint4 v = *(const uint4*)(qkv + (rowbase + row) * 2304 + 768 + h * 64 + c8);
    *(uint4*)(smem + row * 128 + ((c8 * 2) ^ ((row & 7) << 4))) = v;
  }
  // stage V transposed: Vt[d][k], k rows 0..287
  for (int i = tid; i < 288 * 8; i += 512) {
    const int row = i >> 3, c8 = (i & 7) << 3;
    union { u16 u[8]; uint4 v; } t;
    t.v = *(const uint4*)(qkv + (rowbase + row) * 2304 + 1536 + h * 64 + c8);
#pragma unroll
    for (int j = 0; j < 8; ++j) {
      const int d = c8 + j;
      const int sw = ((row < 256) ? (d & 7) : (d & 3)) << 4;
      *(u16*)(smem + 34816 + d * 576 + ((row * 2) ^ sw)) = t.u[j];
    }
  }
  __syncthreads();

  const int fr = lane & 15, g = lane >> 4;
  char* pcb = smem + 71680 + (w << 10);   // 1KB per wave, single-buffered
  const f32x4 vz = {0.f, 0.f, 0.f, 0.f};

  for (int qt = w; qt < 13; qt += 8) {
    const u16* qp = qkv + (rowbase + qt * 16 + fr) * 2304 + h * 64 + g * 8;
    half8 aq0 = *(const half8*)qp;
    half8 aq1 = *(const half8*)(qp + 32);
    aq0 = aq0 * (_Float16)0.125;   // fold softmax scale (exact pow2)
    aq1 = aq1 * (_Float16)0.125;

    f32x4 sc[17];
#pragma unroll
    for (int jt = 0; jt < 17; ++jt) {
      const int krow = jt * 16 + fr;
      const int swz = (krow & 7) << 4;
      half8 bk0 = *(const half8*)(smem + krow * 128 + ((g * 16) ^ swz));
      half8 bk1 = *(const half8*)(smem + krow * 128 + ((64 + g * 16) ^ swz));
      f32x4 a = vz;
      a = __builtin_amdgcn_mfma_f32_16x16x32_f16(aq0, bk0, a, 0, 0, 0);
      a = __builtin_amdgcn_mfma_f32_16x16x32_f16(aq1, bk1, a, 0, 0, 0);
      sc[jt] = a;
    }
    // mask: k = jt*16+fr -> only jt=16, fr>=5 invalid (k>=261)
    if (fr >= 5) {
#pragma unroll
      for (int ri = 0; ri < 4; ++ri) sc[16][ri] = -3.0e38f;
    }
    // softmax (k-rows live across the 16 lanes of each 16-lane group)
#pragma unroll
    for (int ri = 0; ri < 4; ++ri) {
      float m = sc[0][ri];
#pragma unroll
      for (int jt = 1; jt < 17; ++jt) m = fmaxf(m, sc[jt][ri]);
#pragma unroll
      for (int off = 1; off <= 8; off <<= 1) m = fmaxf(m, __shfl_xor(m, off, 64));
      float s = 0.f;
#pragma unroll
      for (int jt = 0; jt < 17; ++jt) {
        float e = __expf(sc[jt][ri] - m);
        sc[jt][ri] = e;
        s += e;
      }
#pragma unroll
      for (int off = 1; off <= 8; off <<= 1) s += __shfl_xor(s, off, 64);
      const float inv = 1.f / s;
#pragma unroll
      for (int jt = 0; jt < 17; ++jt) sc[jt][ri] *= inv;
    }
    // attn_out store (first 197 cols) — proven-clean col=fr pattern
    const int q0r = qt * 16 + g * 4;
    {
      float* ob = out + ATTN_OFF + (size_t)bid * NQ * NQ;
#pragma unroll
      for (int jt = 0; jt < 13; ++jt) {
        const int col = jt * 16 + fr;
        if (col < NQ) {
#pragma unroll
          for (int ri = 0; ri < 4; ++ri) {
            const int qr = q0r + ri;
            if (qr < NQ) ob[(size_t)qr * NQ + col] = sc[jt][ri];
          }
        }
      }
    }
    // P @ V — per-wave single 1KB LDS chunk (DS ops in-order per wave;
    // explicit drain covers the write->read RAW)
    f32x4 oa[4] = {vz, vz, vz, vz};
#pragma unroll
    for (int kt = 0; kt < 9; ++kt) {
#pragma unroll
      for (int hf = 0; hf < 2; ++hf) {
        const int jt = kt * 2 + hf;
#pragma unroll
        for (int ri = 0; ri < 4; ++ri) {
          const int prow = g * 4 + ri, pcol = hf * 16 + fr;
          const float v = (jt < 17) ? sc[jt][ri] : 0.f;
          *(u16*)(pcb + prow * 64 + ((pcol * 2) ^ ((prow & 3) << 4))) = f2h(v);
        }
      }
      asm volatile("s_waitcnt lgkmcnt(0)" ::: "memory");
      __builtin_amdgcn_sched_barrier(0);
      half8 pa = *(const half8*)(pcb + fr * 64 + ((g * 16) ^ ((fr & 3) << 4)));
#pragma unroll
      for (int dt = 0; dt < 4; ++dt) {
        const int vrow = dt * 16 + fr;
        const int sw = ((kt < 8) ? (vrow & 7) : (vrow & 3)) << 4;
        half8 bv = *(const half8*)(smem + 34816 + vrow * 576 + ((kt * 64 + g * 16) ^ sw));
        oa[dt] = __builtin_amdgcn_mfma_f32_16x16x32_f16(pa, bv, oa[dt], 0, 0, 0);
      }
    }
    // store O (fp16)
#pragma unroll
    for (int dt = 0; dt < 4; ++dt)
#pragma unroll
      for (int ri = 0; ri < 4; ++ri) {
        const int qr = q0r + ri;
        if (qr < NQ)
          Oh[((size_t)b * NQ + qr) * 768 + h * 64 + dt * 16 + fr] = f2h(oa[dt][ri]);
      }
  }
}

// ---------------- fp32 saliency side path (exact top-k), parallelized --------
__global__ void sal_q0(const float* __restrict__ src, const float* __restrict__ Wq,
                       float* __restrict__ q0ws) {
  const int bid = blockIdx.x;            // 64*192
  const int b = bid / 192, cb = (bid - (bid / 192) * 192) * 4;
  const int w = threadIdx.x >> 6, lane = threadIdx.x & 63;
  const int c = cb + w;
  const float* srow = src + (size_t)b * NQ * 768;
  const float* wrow = Wq + (size_t)c * 768;
  float acc = 0.f;
#pragma unroll
  for (int j = 0; j < 12; ++j)
    acc = fmaf(srow[lane + 64 * j], wrow[lane + 64 * j], acc);
#pragma unroll
  for (int off = 32; off >= 1; off >>= 1) acc += __shfl_xor(acc, off, 64);
  if (lane == 0) q0ws[(size_t)b * 768 + c] = acc;
}

__global__ void sal_r(const float* __restrict__ q0ws, const float* __restrict__ Wk,
                      float* __restrict__ rws) {
  const int bid = blockIdx.x;            // 64*12*3 = 2304
  const int b = bid / 36, rem = bid - (bid / 36) * 36;
  const int h = rem / 3, cc = (rem - (rem / 3) * 3) * 256;
  const int c = cc + threadIdx.x;
  __shared__ float sq[64];
  if (threadIdx.x < 64) sq[threadIdx.x] = q0ws[(size_t)b * 768 + h * 64 + threadIdx.x];
  __syncthreads();
  float acc = 0.f;
#pragma unroll
  for (int dh = 0; dh < 64; ++dh)
    acc = fmaf(sq[dh], Wk[(size_t)(h * 64 + dh) * 768 + c], acc);
  rws[((size_t)b * 12 + h) * 768 + c] = acc;
}

__global__ void sal_p(const float* __restrict__ src, const float* __restrict__ vtm,
                      const float* __restrict__ rws, float* __restrict__ pws) {
  const int bid = blockIdx.x;            // 64*261 = 16704
  const int b = bid / NKV, kk = bid - (bid / NKV) * NKV;
  const int w = threadIdx.x >> 6, lane = threadIdx.x & 63;
  const float* kvrow;
  if (kk < NQ) kvrow = src + ((size_t)b * NQ + kk) * 768;
  else {
    int tt = kk - NQ;
    kvrow = vtm + ((size_t)((tt >> 4) * 64 + b) * 16 + (tt & 15)) * 768;
  }
  float v[12];
#pragma unroll
  for (int j = 0; j < 12; ++j) v[j] = kvrow[lane + 64 * j];
  for (int hh = w; hh < 12; hh += 4) {
    const float* rrow = rws + ((size_t)b * 12 + hh) * 768;
    float acc = 0.f;
#pragma unroll
    for (int j = 0; j < 12; ++j) acc = fmaf(v[j], rrow[lane + 64 * j], acc);
#pragma unroll
    for (int off = 32; off >= 1; off >>= 1) acc += __shfl_xor(acc, off, 64);
    if (lane == 0) pws[((size_t)b * 12 + hh) * NKV + kk] = acc * 0.125f;
  }
}

__global__ void sal_top(const float* __restrict__ src, const float* __restrict__ pws,
                        float* __restrict__ out) {
  const int b = blockIdx.x, tid = threadIdx.x, w = tid >> 6, lane = tid & 63;
  __shared__ float s_p[12][272];
  __shared__ float s_sal[196];
  __shared__ int s_top[16];
  for (int i = tid; i < 12 * NKV; i += 256)
    s_p[i / NKV][i - (i / NKV) * NKV] = pws[(size_t)b * 12 * NKV + i];
  __syncthreads();
  for (int hh = w; hh < 12; hh += 4) {
    float m = -3.0e38f;
    for (int kk = lane; kk < NKV; kk += 64) m = fmaxf(m, s_p[hh][kk]);
#pragma unroll
    for (int off = 32; off >= 1; off >>= 1) m = fmaxf(m, __shfl_xor(m, off, 64));
    float s = 0.f;
    for (int kk = lane; kk < NKV; kk += 64) s += expf(s_p[hh][kk] - m);
#pragma unroll
    for (int off = 32; off >= 1; off >>= 1) s += __shfl_xor(s, off, 64);
    for (int kk = lane; kk < NKV; kk += 64) s_p[hh][kk] = expf(s_p[hh][kk] - m) / s;
  }
  __syncthreads();
  if (tid < 196) {
    float a = 0.f;
#pragma unroll
    for (int hh = 0; hh < 12; ++hh) a += s_p[hh][tid + 1];
    s_sal[tid] = a * (1.0f / 12.0f);
  }
  __syncthreads();
  if (w == 0) {
    float v[4];
    int idx[4];
    bool taken[4];
#pragma unroll
    for (int j = 0; j < 4; ++j) {
      int id = lane + 64 * j;
      idx[j] = id;
      taken[j] = false;
      v[j] = (id < 196) ? s_sal[id] : -3.0e38f;
    }
    for (int round = 0; round < 16; ++round) {
      float best = -3.0e38f;
      int bi = 1 << 30;
#pragma unroll
      for (int j = 0; j < 4; ++j)
        if (!taken[j] && v[j] > best) { best = v[j]; bi = idx[j]; }
#pragma unroll
      for (int off = 1; off <= 32; off <<= 1) {
        float ov = __shfl_xor(best, off, 64);
        int oi = __shfl_xor(bi, off, 64);
        if (ov > best || (ov == best && oi < bi)) { best = ov; bi = oi; }
      }
#pragma unroll
      for (int j = 0; j < 4; ++j)
        if (idx[j] == bi) taken[j] = true;
      if (lane == 0) s_top[round] = bi;
    }
  }
  __syncthreads();
  for (int i = 0; i < 16; ++i) {
    int id = s_top[i];
    for (int c = tid; c < 768; c += 256)
      out[SAL_OFF + ((size_t)b * 16 + i) * 768 + c] = src[((size_t)b * NQ + id) * 768 + c];
  }
}

// ---------------- launcher ----------------------------------------------------
extern "C" void kernel_launch(void* const* d_in, const int* in_sizes, int n_in,
                              void* d_out, int out_size, void* d_ws, size_t ws_size,
                              hipStream_t stream) {
  const float* src = (const float*)d_in[0];
  const float* vtm = (const float*)d_in[1];
  const float* Wq = (const float*)d_in[2];
  const float* Wk = (const float*)d_in[3];
  const float* Wv = (const float*)d_in[4];
  const float* Wp = (const float*)d_in[5];
  const float* bp = (const float*)d_in[6];
  float* out = (float*)d_out;
  char* ws = (char*)d_ws;

  u16* Wqkv = (u16*)(ws + WS_WQKV);
  u16* Wph = (u16*)(ws + WS_WP);
  u16* kvh = (u16*)(ws + WS_KV);
  u16* QKV = (u16*)(ws + WS_QKV);
  u16* Oh = (u16*)(ws + WS_O);
  float* q0ws = (float*)(ws + WS_Q0);
  float* pws = (float*)(ws + WS_P);
  float* rws = (float*)(ws + WS_R);

  prep<<<3200, 256, 0, stream>>>(Wq, Wk, Wv, Wp, src, vtm, Wqkv, Wph, kvh);
  // QKV = kv @ [Wq;Wk;Wv]^T   (M=16768, N=2304, K=768) — nt-fast order
  gemm_bt<0><<<131 * 18, 256, 0, stream>>>(kvh, Wqkv, QKV, nullptr, 18, 768, 768, 768, 2304, 0);
  hipFuncSetAttribute((const void*)attn_kernel, hipFuncAttributeMaxDynamicSharedMemorySize,
                      ATT_LDS_TOT);
  attn_kernel<<<B_ * H_, 512, ATT_LDS_TOT, stream>>>(QKV, out, Oh);
  // x = O @ Wp^T + bp  (M=12672, real 12608, N=768, K=768) — nt-fast order
  gemm_bt<1><<<99 * 6, 256, 0, stream>>>(Oh, Wph, out, bp, 6, 768, 768, 768, 768, 12608);
  // fp32 saliency side path (exact top-k), parallelized — scratch aliases kvh
  sal_q0<<<64 * 192, 256, 0, stream>>>(src, Wq, q0ws);
  sal_r<<<64 * 12 * 3, 256, 0, stream>>>(q0ws, Wk, rws);
  sal_p<<<64 * NKV, 256, 0, stream>>>(src, vtm, rws, pws);
  sal_top<<<64, 256, 0, stream>>>(src, pws, out);
}